// Round 2
// baseline (2839.155 us; speedup 1.0000x reference)
//
#include <hip/hip_runtime.h>
#include <hip/hip_bf16.h>

// DeformConvBlock B=4,C=64,H=W=256,OUT=64.
// Round 2: NHWC bf16 staging of x + wave-uniform (scalar-pipe) weight loads.
// K0: transpose weights to [tap][o][c] fp32 in ws.
// K1: transpose x CHW fp32 -> xt NHWC bf16 in ws.
// K2: fused offset-conv (fp32, reads original x, coalesced) + deform gather
//     (bf16 NHWC, 16B vector loads) + 64x576 matvec (fp32 VALU).
// Wave layout K2 phase2: wave w -> outputs w*16..w*16+15 (uniform -> s_load
// weights), lane -> pixel quad. XCD band swizzle for L2 row locality.

namespace {
constexpr int B_ = 4, C_ = 64, H_ = 256, W_ = 256, OUT_ = 64;
constexpr int HW_ = H_ * W_;
// ws carve-up
constexpr size_t XT_BYTES   = (size_t)B_ * H_ * W_ * C_ * 2;   // 32 MB bf16 NHWC
constexpr size_t WOFF_OFF   = XT_BYTES;                        // [9][18][64] fp32
constexpr size_t WOFF_BYTES = 9 * 18 * 64 * 4;
constexpr size_t WDEF_OFF   = WOFF_OFF + ((WOFF_BYTES + 255) / 256) * 256; // [9][64][64] fp32
}

// ---------------- K0: weight transpose ----------------
__global__ void prep_weights(const float* __restrict__ w_off,
                             const float* __restrict__ w_def,
                             float* __restrict__ wt_off,
                             float* __restrict__ wt_def)
{
    const int i0 = blockIdx.x * 256 + threadIdx.x;
    const int stride = gridDim.x * 256;
    for (int i = i0; i < 9 * 18 * 64; i += stride) {
        const int tap = i / (18 * 64);
        const int r = i - tap * 18 * 64;
        const int j = r >> 6, c = r & 63;
        wt_off[i] = w_off[(j * 64 + c) * 9 + tap];
    }
    for (int i = i0; i < 9 * 64 * 64; i += stride) {
        const int tap = i >> 12;
        const int r = i & 4095;
        const int o = r >> 6, c = r & 63;
        wt_def[i] = w_def[(o * 64 + c) * 9 + tap];
    }
}

// ---------------- K1: x CHW fp32 -> NHWC bf16 ----------------
__global__ __launch_bounds__(256)
void transpose_x(const float* __restrict__ x, __hip_bfloat16* __restrict__ xt)
{
    __shared__ float tile[64 * 65];
    const int bid = blockIdx.x;           // ((b*256+y)*4 + xchunk)
    const int xc = bid & 3;
    const int y = (bid >> 2) & 255;
    const int b = bid >> 10;
    const int px0 = xc * 64;
    const float* __restrict__ xp = x + (size_t)b * C_ * HW_ + y * W_ + px0;

    for (int i = threadIdx.x; i < 64 * 64; i += 256) {
        const int c = i >> 6, px = i & 63;              // lanes sweep px -> coalesced
        tile[px * 65 + c] = xp[(size_t)c * HW_ + px];
    }
    __syncthreads();

    const int px = threadIdx.x >> 2;
    const int cs = (threadIdx.x & 3) * 16;
    __hip_bfloat16 hv[16];
#pragma unroll
    for (int k = 0; k < 16; ++k) hv[k] = __float2bfloat16(tile[px * 65 + cs + k]);
    __hip_bfloat16* dst = xt + (((size_t)(b * H_ + y)) * W_ + px0 + px) * C_ + cs;
    ((uint4*)dst)[0] = ((const uint4*)hv)[0];
    ((uint4*)dst)[1] = ((const uint4*)hv)[1];
}

// ---------------- K2: fused deform conv ----------------
__device__ __forceinline__ void bilin_setup(float ys, float xs, int* a, float* w)
{
    const float y0f = floorf(ys), x0f = floorf(xs);
    const float ly = ys - y0f, lx = xs - x0f;
    const int y0 = (int)y0f, x0 = (int)x0f;
    const int y1 = y0 + 1, x1 = x0 + 1;
    const int y0c = min(max(y0, 0), H_ - 1);
    const int y1c = min(max(y1, 0), H_ - 1);
    const int x0c = min(max(x0, 0), W_ - 1);
    const int x1c = min(max(x1, 0), W_ - 1);
    const float fy0 = (y0 >= 0 && y0 < H_) ? 1.0f : 0.0f;
    const float fy1 = (y1 >= 0 && y1 < H_) ? 1.0f : 0.0f;
    const float fx0 = (x0 >= 0 && x0 < W_) ? 1.0f : 0.0f;
    const float fx1 = (x1 >= 0 && x1 < W_) ? 1.0f : 0.0f;
    a[0] = y0c * W_ + x0c;  w[0] = (1.0f - ly) * (1.0f - lx) * fy0 * fx0;
    a[1] = y0c * W_ + x1c;  w[1] = (1.0f - ly) * lx          * fy0 * fx1;
    a[2] = y1c * W_ + x0c;  w[2] = ly          * (1.0f - lx) * fy1 * fx0;
    a[3] = y1c * W_ + x1c;  w[3] = ly          * lx          * fy1 * fx1;
}

__device__ __forceinline__ void blend8(uint4 u0, uint4 u1, uint4 u2, uint4 u3,
                                       const float* __restrict__ w,
                                       float* __restrict__ s)
{
    const unsigned int* a = &u0.x;
    const unsigned int* b = &u1.x;
    const unsigned int* c = &u2.x;
    const unsigned int* d = &u3.x;
#pragma unroll
    for (int k = 0; k < 4; ++k) {
        const float a0 = __uint_as_float(a[k] << 16);
        const float a1 = __uint_as_float(a[k] & 0xffff0000u);
        const float b0 = __uint_as_float(b[k] << 16);
        const float b1 = __uint_as_float(b[k] & 0xffff0000u);
        const float c0 = __uint_as_float(c[k] << 16);
        const float c1 = __uint_as_float(c[k] & 0xffff0000u);
        const float d0 = __uint_as_float(d[k] << 16);
        const float d1 = __uint_as_float(d[k] & 0xffff0000u);
        s[2 * k]     = w[0] * a0 + w[1] * b0 + w[2] * c0 + w[3] * d0;
        s[2 * k + 1] = w[0] * a1 + w[1] * b1 + w[2] * c1 + w[3] * d1;
    }
}

__global__ __launch_bounds__(256, 2)
void deform_main(const float* __restrict__ x,
                 const __hip_bfloat16* __restrict__ xt,
                 const float* __restrict__ wt_off,
                 const float* __restrict__ b_off,
                 const float* __restrict__ wt_def,
                 const float* __restrict__ b_def,
                 float* __restrict__ out)
{
    __shared__ float off_lds[256 * 19];   // stride 19: conflict-free-ish
    const int tid = threadIdx.x;
    const int bid = blockIdx.x;
    const int row = (bid & 7) * 128 + (bid >> 3);   // XCD band swizzle (1024 blocks)
    const int b = row >> 8;
    const int y = row & 255;
    const float* __restrict__ xb = x + (size_t)b * C_ * HW_;
    const __hip_bfloat16* __restrict__ xtb = xt + (size_t)b * HW_ * C_;

    // ---- phase 1: offset conv, thread = pixel, fp32, weights via scalar pipe ----
    {
        const int px = tid;
        float acc1[18];
#pragma unroll
        for (int j = 0; j < 18; ++j) acc1[j] = b_off[j];

#pragma unroll 1
        for (int tap = 0; tap < 9; ++tap) {
            const int ki = tap / 3, kj = tap % 3;
            const int yy = y + ki - 1;
            const int xx = px + kj - 1;
            const bool valid = (yy >= 0) && (yy < H_) && (xx >= 0) && (xx < W_);
            const int aoff = valid ? (yy * W_ + xx) : 0;
            const float mask = valid ? 1.0f : 0.0f;
            const float4* __restrict__ wp = (const float4*)(wt_off + tap * 18 * 64);
#pragma unroll 4
            for (int cg = 0; cg < 16; ++cg) {
                const float v0 = xb[(cg * 4 + 0) * HW_ + aoff] * mask;
                const float v1 = xb[(cg * 4 + 1) * HW_ + aoff] * mask;
                const float v2 = xb[(cg * 4 + 2) * HW_ + aoff] * mask;
                const float v3 = xb[(cg * 4 + 3) * HW_ + aoff] * mask;
#pragma unroll
                for (int j = 0; j < 18; ++j) {
                    const float4 w = wp[j * 16 + cg];   // wave-uniform -> s_load
                    acc1[j] += v0 * w.x + v1 * w.y + v2 * w.z + v3 * w.w;
                }
            }
        }
#pragma unroll
        for (int j = 0; j < 18; ++j) off_lds[px * 19 + j] = acc1[j];
    }
    __syncthreads();

    // ---- phase 2: wave = 16 outputs (uniform), lane = pixel quad ----
    const int q = tid & 63;            // lane -> pixel quad
    const int osel = (tid >> 6) * 16;  // wave -> output block (uniform!)
    const int px0 = q * 4;

    float acc[4][16];
#pragma unroll
    for (int p = 0; p < 4; ++p)
#pragma unroll
        for (int oo = 0; oo < 16; ++oo) acc[p][oo] = 0.0f;

#pragma unroll 1
    for (int tap = 0; tap < 9; ++tap) {
        const int ki = tap / 3, kj = tap % 3;
        int ca[4][4];
        float cw[4][4];
#pragma unroll
        for (int p = 0; p < 4; ++p) {
            const int px = px0 + p;
            const float ys = (float)(y + ki - 1) + off_lds[px * 19 + tap * 2];
            const float xs = (float)(px + kj - 1) + off_lds[px * 19 + tap * 2 + 1];
            bilin_setup(ys, xs, ca[p], cw[p]);
        }
        const float4* __restrict__ w2 =
            (const float4*)(wt_def + tap * 64 * 64) + osel * 16;

#pragma unroll 1
        for (int cg = 0; cg < 8; ++cg) {   // 8 channels per chunk
            float s[4][8];
#pragma unroll
            for (int p = 0; p < 4; ++p) {
                const uint4 u0 = *((const uint4*)(xtb + (size_t)ca[p][0] * 64) + cg);
                const uint4 u1 = *((const uint4*)(xtb + (size_t)ca[p][1] * 64) + cg);
                const uint4 u2 = *((const uint4*)(xtb + (size_t)ca[p][2] * 64) + cg);
                const uint4 u3 = *((const uint4*)(xtb + (size_t)ca[p][3] * 64) + cg);
                blend8(u0, u1, u2, u3, cw[p], s[p]);
            }
#pragma unroll
            for (int oo = 0; oo < 16; ++oo) {
                const float4 wa = w2[oo * 16 + cg * 2];       // uniform -> s_load
                const float4 wb = w2[oo * 16 + cg * 2 + 1];
#pragma unroll
                for (int p = 0; p < 4; ++p) {
                    acc[p][oo] += s[p][0] * wa.x + s[p][1] * wa.y
                                + s[p][2] * wa.z + s[p][3] * wa.w
                                + s[p][4] * wb.x + s[p][5] * wb.y
                                + s[p][6] * wb.z + s[p][7] * wb.w;
                }
            }
        }
    }

    // ---- epilogue: float4 stores, wave-contiguous 1 KB per instr ----
#pragma unroll
    for (int oo = 0; oo < 16; ++oo) {
        const int o = osel + oo;
        const float bd = b_def[o];
        const float4 v = make_float4(acc[0][oo] + bd, acc[1][oo] + bd,
                                     acc[2][oo] + bd, acc[3][oo] + bd);
        *(float4*)&out[(((size_t)b * OUT_ + o) * H_ + y) * W_ + px0] = v;
    }
}

extern "C" void kernel_launch(void* const* d_in, const int* in_sizes, int n_in,
                              void* d_out, int out_size, void* d_ws, size_t ws_size,
                              hipStream_t stream)
{
    const float* x     = (const float*)d_in[0];
    const float* w_off = (const float*)d_in[1];
    const float* b_off = (const float*)d_in[2];
    const float* w_def = (const float*)d_in[3];
    const float* b_def = (const float*)d_in[4];
    float* out = (float*)d_out;

    __hip_bfloat16* xt = (__hip_bfloat16*)d_ws;
    float* wt_off = (float*)((char*)d_ws + WOFF_OFF);
    float* wt_def = (float*)((char*)d_ws + WDEF_OFF);

    prep_weights<<<dim3(32), dim3(256), 0, stream>>>(w_off, w_def, wt_off, wt_def);
    transpose_x<<<dim3(B_ * H_ * 4), dim3(256), 0, stream>>>(x, xt);
    deform_main<<<dim3(B_ * H_), dim3(256), 0, stream>>>(
        x, xt, wt_off, b_off, wt_def, b_def, out);
}

// Round 3
// 336.054 us; speedup vs baseline: 8.4485x; 8.4485x over previous
//
#include <hip/hip_runtime.h>
#include <hip/hip_bf16.h>

// DeformConvBlock B=4,C=64,H=W=256,OUT=64 — MFMA version.
// K0 prep: rearrange w_off/w_def into bf16 MFMA B-fragment order in ws.
// K1: x CHW fp32 -> xt NHWC bf16 (ws).
// K2: per row-block: phase1 offsets via MFMA (A direct from xt global),
//     phase2 bilinear blend (fp32 VALU) -> XOR-swizzled LDS -> MFMA matmul.
// mfma_f32_16x16x32_bf16: A[m=lane&15][k=(lane>>4)*8+j], B[k][n=lane&15],
// D col=lane&15, row=(lane>>4)*4+reg  (per verified guide layouts).

typedef short short8 __attribute__((ext_vector_type(8)));
typedef float floatx4 __attribute__((ext_vector_type(4)));

namespace {
constexpr int B_ = 4, C_ = 64, H_ = 256, W_ = 256, OUT_ = 64;
constexpr int HW_ = H_ * W_;
constexpr size_t XT_BYTES = (size_t)B_ * HW_ * C_ * 2;      // 32 MB NHWC bf16
constexpr size_t WOFF_OFF = XT_BYTES;                        // [9][2][2][64][8] bf16
constexpr int    WOFF_N   = 9 * 2 * 2 * 64 * 8;              // 18432
constexpr size_t WDEF_OFF = WOFF_OFF + (size_t)WOFF_N * 2;   // [9][2][4][64][8] bf16
constexpr int    WDEF_N   = 9 * 2 * 4 * 64 * 8;              // 36864
}

// ---------------- K0: weights -> B-fragment order (bf16) ----------------
__global__ void prep_weights(const float* __restrict__ w_off,
                             const float* __restrict__ w_def,
                             __hip_bfloat16* __restrict__ wof,
                             __hip_bfloat16* __restrict__ wdf)
{
    const int i0 = blockIdx.x * 256 + threadIdx.x;
    const int stride = gridDim.x * 256;
    for (int i = i0; i < WOFF_N; i += stride) {
        const int jj = i & 7, lane = (i >> 3) & 63, nt = (i >> 9) & 1;
        const int kc = (i >> 10) & 1, tap = i >> 11;
        const int c = kc * 32 + (lane >> 4) * 8 + jj;
        const int n = nt * 16 + (lane & 15);
        const float v = (n < 18) ? w_off[(n * 64 + c) * 9 + tap] : 0.0f;
        wof[i] = __float2bfloat16(v);
    }
    for (int i = i0; i < WDEF_N; i += stride) {
        const int jj = i & 7, lane = (i >> 3) & 63, ot = (i >> 9) & 3;
        const int kc = (i >> 11) & 1, tap = i >> 12;
        const int c = kc * 32 + (lane >> 4) * 8 + jj;
        const int n = ot * 16 + (lane & 15);
        wdf[i] = __float2bfloat16(w_def[(n * 64 + c) * 9 + tap]);
    }
}

// ---------------- K1: x CHW fp32 -> NHWC bf16 ----------------
__global__ __launch_bounds__(256)
void transpose_x(const float* __restrict__ x, __hip_bfloat16* __restrict__ xt)
{
    __shared__ float tile[64 * 65];
    const int bid = blockIdx.x;           // ((b*256+y)*4 + xchunk)
    const int xc = bid & 3;
    const int y = (bid >> 2) & 255;
    const int b = bid >> 10;
    const int px0 = xc * 64;
    const float* __restrict__ xp = x + (size_t)b * C_ * HW_ + y * W_ + px0;

    for (int i = threadIdx.x; i < 64 * 64; i += 256) {
        const int c = i >> 6, px = i & 63;
        tile[px * 65 + c] = xp[(size_t)c * HW_ + px];
    }
    __syncthreads();

    const int px = threadIdx.x >> 2;
    const int cs = (threadIdx.x & 3) * 16;
    __hip_bfloat16 hv[16];
#pragma unroll
    for (int k = 0; k < 16; ++k) hv[k] = __float2bfloat16(tile[px * 65 + cs + k]);
    __hip_bfloat16* dst = xt + (((size_t)(b * H_ + y)) * W_ + px0 + px) * C_ + cs;
    ((uint4*)dst)[0] = ((const uint4*)hv)[0];
    ((uint4*)dst)[1] = ((const uint4*)hv)[1];
}

// ---------------- K2 helpers ----------------
__device__ __forceinline__ void bilin_setup(float ys, float xs, int* a, float* w)
{
    const float y0f = floorf(ys), x0f = floorf(xs);
    const float ly = ys - y0f, lx = xs - x0f;
    const int y0 = (int)y0f, x0 = (int)x0f;
    const int y1 = y0 + 1, x1 = x0 + 1;
    const int y0c = min(max(y0, 0), H_ - 1);
    const int y1c = min(max(y1, 0), H_ - 1);
    const int x0c = min(max(x0, 0), W_ - 1);
    const int x1c = min(max(x1, 0), W_ - 1);
    const float fy0 = (y0 >= 0 && y0 < H_) ? 1.0f : 0.0f;
    const float fy1 = (y1 >= 0 && y1 < H_) ? 1.0f : 0.0f;
    const float fx0 = (x0 >= 0 && x0 < W_) ? 1.0f : 0.0f;
    const float fx1 = (x1 >= 0 && x1 < W_) ? 1.0f : 0.0f;
    a[0] = y0c * W_ + x0c;  w[0] = (1.0f - ly) * (1.0f - lx) * fy0 * fx0;
    a[1] = y0c * W_ + x1c;  w[1] = (1.0f - ly) * lx          * fy0 * fx1;
    a[2] = y1c * W_ + x0c;  w[2] = ly          * (1.0f - lx) * fy1 * fx0;
    a[3] = y1c * W_ + x1c;  w[3] = ly          * lx          * fy1 * fx1;
}

// blend 8 bf16 channels (packed in 2 dwords per corner x2) in fp32
__device__ __forceinline__ void blend8(uint4 ua, uint4 ub, uint4 uc, uint4 ud,
                                       const float* __restrict__ w,
                                       float* __restrict__ s)
{
    const unsigned int* a = &ua.x;
    const unsigned int* b = &ub.x;
    const unsigned int* c = &uc.x;
    const unsigned int* d = &ud.x;
#pragma unroll
    for (int k = 0; k < 4; ++k) {
        const float a0 = __uint_as_float(a[k] << 16);
        const float a1 = __uint_as_float(a[k] & 0xffff0000u);
        const float b0 = __uint_as_float(b[k] << 16);
        const float b1 = __uint_as_float(b[k] & 0xffff0000u);
        const float c0 = __uint_as_float(c[k] << 16);
        const float c1 = __uint_as_float(c[k] & 0xffff0000u);
        const float d0 = __uint_as_float(d[k] << 16);
        const float d1 = __uint_as_float(d[k] & 0xffff0000u);
        s[2 * k]     = w[0] * a0 + w[1] * b0 + w[2] * c0 + w[3] * d0;
        s[2 * k + 1] = w[0] * a1 + w[1] * b1 + w[2] * c1 + w[3] * d1;
    }
}

// ---------------- K2: fused deform conv (MFMA) ----------------
__global__ __launch_bounds__(256, 3)
void deform_main(const __hip_bfloat16* __restrict__ xt,
                 const __hip_bfloat16* __restrict__ wof,
                 const float* __restrict__ b_off,
                 const __hip_bfloat16* __restrict__ wdf,
                 const float* __restrict__ b_def,
                 float* __restrict__ out)
{
    __shared__ __hip_bfloat16 smp[256 * 64];  // sampled, XOR-swizzled ch-groups
    __shared__ float off_lds[256 * 18];       // per-pixel offsets

    const int tid = threadIdx.x;
    const int lane = tid & 63;
    const int wv = tid >> 6;            // wave id: px range [wv*64, wv*64+64)
    const int lm = lane & 15;           // m / n index within a 16-tile
    const int lq = lane >> 4;           // quad
    const int bid = blockIdx.x;
    const int row = (bid & 7) * 128 + (bid >> 3);   // XCD band swizzle
    const int b = row >> 8, y = row & 255;
    const __hip_bfloat16* __restrict__ xtb = xt + (size_t)b * HW_ * C_;

    // ================= phase 1: offsets via MFMA =================
    {
        floatx4 acc1[4][2];
#pragma unroll
        for (int pt = 0; pt < 4; ++pt)
#pragma unroll
            for (int nt = 0; nt < 2; ++nt) acc1[pt][nt] = (floatx4)0.0f;

#pragma unroll 1
        for (int tap = 0; tap < 9; ++tap) {
            const int dy = tap / 3 - 1, dx = tap % 3 - 1;
            const int ys = y + dy;
            if ((unsigned)ys < 256u) {
#pragma unroll
                for (int kc = 0; kc < 2; ++kc) {
                    short8 bfr[2];
#pragma unroll
                    for (int nt = 0; nt < 2; ++nt)
                        bfr[nt] = *(const short8*)(wof +
                            ((size_t)(((tap * 2 + kc) * 2 + nt) * 64 + lane)) * 8);
                    short8 afr[4];
#pragma unroll
                    for (int pt = 0; pt < 4; ++pt) {
                        const int px_s = wv * 64 + pt * 16 + lm + dx;
                        const bool vld = (unsigned)px_s < 256u;
                        const int pxc = min(max(px_s, 0), 255);
                        uint4 t = *(const uint4*)(xtb +
                            ((size_t)ys * 256 + pxc) * 64 + kc * 32 + lq * 8);
                        if (!vld) { t.x = 0u; t.y = 0u; t.z = 0u; t.w = 0u; }
                        afr[pt] = __builtin_bit_cast(short8, t);
                    }
#pragma unroll
                    for (int pt = 0; pt < 4; ++pt)
#pragma unroll
                        for (int nt = 0; nt < 2; ++nt)
                            acc1[pt][nt] = __builtin_amdgcn_mfma_f32_16x16x32_bf16(
                                afr[pt], bfr[nt], acc1[pt][nt], 0, 0, 0);
                }
            }
        }
        // scatter offsets (+bias) to LDS: off_lds[px][j]
#pragma unroll
        for (int nt = 0; nt < 2; ++nt) {
            const int j = nt * 16 + lm;
            if (j < 18) {
                const float bj = b_off[j];
#pragma unroll
                for (int pt = 0; pt < 4; ++pt) {
#pragma unroll
                    for (int r = 0; r < 4; ++r) {
                        const int px = wv * 64 + pt * 16 + lq * 4 + r;
                        off_lds[px * 18 + j] = acc1[pt][nt][r] + bj;
                    }
                }
            }
        }
    }

    // ================= phase 2: gather/blend + MFMA =================
    floatx4 acc[4][4];
#pragma unroll
    for (int pt = 0; pt < 4; ++pt)
#pragma unroll
        for (int ot = 0; ot < 4; ++ot) acc[pt][ot] = (floatx4)0.0f;

    const int px = tid;        // gather pixel for this thread
    const int swz = px & 7;    // LDS channel-group XOR swizzle

#pragma unroll 1
    for (int tap = 0; tap < 9; ++tap) {
        __syncthreads();       // previous tap's MFMA reads done (t=0: off_lds ready)
        const int ki = tap / 3, kj = tap % 3;
        {
            const float ys = (float)(y + ki - 1) + off_lds[px * 18 + tap * 2];
            const float xs = (float)(px + kj - 1) + off_lds[px * 18 + tap * 2 + 1];
            int ca[4]; float cw[4];
            bilin_setup(ys, xs, ca, cw);
            const uint4* __restrict__ p0 = (const uint4*)(xtb + (size_t)ca[0] * 64);
            const uint4* __restrict__ p1 = (const uint4*)(xtb + (size_t)ca[1] * 64);
            const uint4* __restrict__ p2 = (const uint4*)(xtb + (size_t)ca[2] * 64);
            const uint4* __restrict__ p3 = (const uint4*)(xtb + (size_t)ca[3] * 64);
#pragma unroll 1
            for (int ch = 0; ch < 4; ++ch) {       // 16 channels per chunk
                const uint4 a0 = p0[ch * 2],     b0 = p1[ch * 2];
                const uint4 c0 = p2[ch * 2],     d0 = p3[ch * 2];
                const uint4 a1 = p0[ch * 2 + 1], b1 = p1[ch * 2 + 1];
                const uint4 c1 = p2[ch * 2 + 1], d1 = p3[ch * 2 + 1];
                float s[16];
                blend8(a0, b0, c0, d0, cw, s);
                blend8(a1, b1, c1, d1, cw, s + 8);
                union { __hip_bfloat16 h[8]; short8 v; } pk0, pk1;
#pragma unroll
                for (int k = 0; k < 8; ++k) pk0.h[k] = __float2bfloat16(s[k]);
#pragma unroll
                for (int k = 0; k < 8; ++k) pk1.h[k] = __float2bfloat16(s[k + 8]);
                const int g0 = ch * 2, g1 = ch * 2 + 1;
                *(short8*)&smp[px * 64 + ((g0 ^ swz) * 8)] = pk0.v;
                *(short8*)&smp[px * 64 + ((g1 ^ swz) * 8)] = pk1.v;
            }
        }
        __syncthreads();       // sampled ready

#pragma unroll
        for (int kc = 0; kc < 2; ++kc) {
            short8 bfr[4];
#pragma unroll
            for (int ot = 0; ot < 4; ++ot)
                bfr[ot] = *(const short8*)(wdf +
                    ((size_t)(((tap * 2 + kc) * 4 + ot) * 64 + lane)) * 8);
            short8 afr[4];
#pragma unroll
            for (int pt = 0; pt < 4; ++pt) {
                const int apx = wv * 64 + pt * 16 + lm;
                const int grp = (kc * 4 + lq) ^ (apx & 7);
                afr[pt] = *(const short8*)&smp[apx * 64 + grp * 8];
            }
#pragma unroll
            for (int pt = 0; pt < 4; ++pt)
#pragma unroll
                for (int ot = 0; ot < 4; ++ot)
                    acc[pt][ot] = __builtin_amdgcn_mfma_f32_16x16x32_bf16(
                        afr[pt], bfr[ot], acc[pt][ot], 0, 0, 0);
        }
    }

    // ================= epilogue: float4 stores =================
#pragma unroll
    for (int ot = 0; ot < 4; ++ot) {
        const int o = ot * 16 + lm;
        const float bd = b_def[o];
#pragma unroll
        for (int pt = 0; pt < 4; ++pt) {
            const int pxs = wv * 64 + pt * 16 + lq * 4;
            const floatx4 a = acc[pt][ot];
            float4 v = make_float4(a[0] + bd, a[1] + bd, a[2] + bd, a[3] + bd);
            *(float4*)&out[(((size_t)b * OUT_ + o) * H_ + y) * W_ + pxs] = v;
        }
    }
}

extern "C" void kernel_launch(void* const* d_in, const int* in_sizes, int n_in,
                              void* d_out, int out_size, void* d_ws, size_t ws_size,
                              hipStream_t stream)
{
    const float* x     = (const float*)d_in[0];
    const float* w_off = (const float*)d_in[1];
    const float* b_off = (const float*)d_in[2];
    const float* w_def = (const float*)d_in[3];
    const float* b_def = (const float*)d_in[4];
    float* out = (float*)d_out;

    __hip_bfloat16* xt  = (__hip_bfloat16*)d_ws;
    __hip_bfloat16* wof = (__hip_bfloat16*)((char*)d_ws + WOFF_OFF);
    __hip_bfloat16* wdf = (__hip_bfloat16*)((char*)d_ws + WDEF_OFF);

    prep_weights<<<dim3(32), dim3(256), 0, stream>>>(w_off, w_def, wof, wdf);
    transpose_x<<<dim3(B_ * H_ * 4), dim3(256), 0, stream>>>(x, xt);
    deform_main<<<dim3(B_ * H_), dim3(256), 0, stream>>>(
        xt, wof, b_off, wdf, b_def, out);
}